// Round 6
// baseline (364.905 us; speedup 1.0000x reference)
//
#include <hip/hip_runtime.h>

#define B_ 256
#define T_ 1024
#define V_ 5000
#define D_ 100
#define H_ 64
#define C_ 2

// ---------------------------------------------------------------------------
// Kernel 1: EW[v][h] = sum_d E[v][d] * W[d][h] + b[h]
// ---------------------------------------------------------------------------
__global__ __launch_bounds__(256) void ew_kernel(const float* __restrict__ E,
                                                 const float* __restrict__ W,
                                                 const float* __restrict__ bias,
                                                 float* __restrict__ EW) {
    int idx = blockIdx.x * 256 + threadIdx.x;   // 0 .. V_*H_
    if (idx >= V_ * H_) return;
    int h = idx & (H_ - 1);
    int v = idx >> 6;
    float acc = bias[h];
    const float* Erow = E + v * D_;
    #pragma unroll 4
    for (int d = 0; d < D_; ++d) {
        acc = fmaf(Erow[d], W[d * H_ + h], acc);
    }
    EW[idx] = acc;
}

// ---------------------------------------------------------------------------
// Kernel 2: RNN, 4 waves per batch element (one per SIMD of a CU).
//
// R5 post-mortem: single wave/SIMD issues back-to-back VALU at ~4 cyc/inst
// (145 insts/step measured ~560 cyc). The serial chain must get SHORTER,
// not wider: split the 64-term dot over 4 waves (16 readlane + 16 fma
// each), exchange partials through LDS with ONE barrier per step
// (double-buffered slots), and let every wave redundantly compute the
// sum + tanh + mask so the replicated h state needs no broadcast step.
// Per-wave serial VALU: ~55 insts/step vs 145.
// ---------------------------------------------------------------------------
__device__ __forceinline__ float readlane_f(float v, int lane) {
    return __uint_as_float(__builtin_amdgcn_readlane(__float_as_uint(v), lane));
}

__global__ __launch_bounds__(256, 1) void rnn_kernel(const int* __restrict__ tokens,
                                                     const float* __restrict__ EW,
                                                     const float* __restrict__ U,
                                                     const float* __restrict__ Wd,
                                                     const float* __restrict__ bd,
                                                     float* __restrict__ out) {
    const int b   = blockIdx.x;          // batch element
    const int tid = threadIdx.x;
    const int w   = tid >> 6;            // wave 0..3  (uniform per wave)
    const int j   = tid & 63;            // lane: hidden unit j

    // U slice for wave w: lane j needs U[i][j], i in [16w,16w+16), as 4
    // float4 chunks. Chunk c stored at slot (c + (j>>1))&3 so that for a
    // fixed c the 64 lanes' b128 reads spread over all 8 bank-quads
    // (8 lanes/quad = b128 baseline, conflict-clean).
    __shared__ float4 sh_U4[4 * H_ * 4];        // 16 KB
    __shared__ float  sh_p[2 * 4 * H_];         // 2 KB partials, dbl-buffered
    __shared__ int    sh_tok[T_ + 2];           // 4 KB + pad

    float* sh_Uf = (float*)sh_U4;
    #pragma unroll
    for (int c = 0; c < 4; ++c) {
        int slot = (c + (j >> 1)) & 3;
        #pragma unroll
        for (int r = 0; r < 4; ++r) {
            int i = (w << 4) + (c << 2) + r;          // global row
            sh_Uf[((((w << 6) + j) << 4)) + (slot << 2) + r] = U[i * H_ + j];
        }
    }
    const int* tok = tokens + b * T_;
    #pragma unroll
    for (int k = 0; k < T_ / 256; ++k) {
        sh_tok[k * 256 + tid] = tok[k * 256 + tid];   // coalesced
    }
    if (tid < 2) sh_tok[T_ + tid] = 0;                // pad: kills tail guard
    __syncthreads();

    // Loop-invariant addresses (float4 index into sh_U4)
    int uaddr[4];
    #pragma unroll
    for (int c = 0; c < 4; ++c)
        uaddr[c] = (((w << 6) + j) << 2) + ((c + (j >> 1)) & 3);
    const int ibase = w << 4;            // wave's first row (uniform -> SGPR)
    const int pw    = (w << 6) + j;      // partial write index (row w)

    float h = 0.f;
    float pooled = 0.f;

    // 2-step-deep xw prefetch pipeline (all waves redundantly; L2-resident)
    int2 tkA = *(const int2*)&sh_tok[0];
    float xw0 = EW[tkA.x * H_ + j];
    float xw1 = EW[tkA.y * H_ + j];

    #define RNN_STEP(buf, tokv, xwv)                                     \
    {                                                                    \
        float a0 = 0.f, a1 = 0.f, a2 = 0.f, a3 = 0.f;                    \
        _Pragma("unroll")                                                \
        for (int c = 0; c < 4; ++c) {                                    \
            const float4 u4 = sh_U4[uaddr[c]];                           \
            int bi = ibase + (c << 2);                                   \
            a0 = fmaf(readlane_f(h, bi + 0), u4.x, a0);                  \
            a1 = fmaf(readlane_f(h, bi + 1), u4.y, a1);                  \
            a2 = fmaf(readlane_f(h, bi + 2), u4.z, a2);                  \
            a3 = fmaf(readlane_f(h, bi + 3), u4.w, a3);                  \
        }                                                                \
        sh_p[(buf) * 256 + pw] = (a0 + a1) + (a2 + a3);                  \
        __syncthreads();                                                 \
        float p0 = sh_p[(buf) * 256 + j];                                \
        float p1 = sh_p[(buf) * 256 + 64 + j];                           \
        float p2 = sh_p[(buf) * 256 + 128 + j];                          \
        float p3 = sh_p[(buf) * 256 + 192 + j];                          \
        float x = ((p0 + p1) + (p2 + p3)) + (xwv);                       \
        float e = __expf(2.f * x);                                       \
        float r = __builtin_amdgcn_rcpf(e + 1.f);                        \
        float hn = fmaf(-2.f, r, 1.f);                                   \
        h = ((tokv) != 0) ? hn : h;                                      \
        pooled += h;                                                     \
    }

    for (int t = 0; t < T_; t += 2) {
        // prefetch steps t+2, t+3 (pad makes tail reads safe: EW[0])
        int2 tkB = *(const int2*)&sh_tok[t + 2];
        float xw2 = EW[tkB.x * H_ + j];
        float xw3 = EW[tkB.y * H_ + j];

        RNN_STEP(0, tkA.x, xw0);
        RNN_STEP(1, tkA.y, xw1);

        tkA = tkB;
        xw0 = xw2;
        xw1 = xw3;
    }
    #undef RNN_STEP

    // ---- epilogue (wave 0 only; its h/pooled replica is complete) ----
    if (w == 0) {
        float p = pooled * (1.0f / (float)T_);
        float v0 = p * Wd[j * C_ + 0];
        float v1 = p * Wd[j * C_ + 1];
        #pragma unroll
        for (int off = 32; off >= 1; off >>= 1) {
            v0 += __shfl_down(v0, off, 64);
            v1 += __shfl_down(v1, off, 64);
        }
        if (j == 0) {
            float l0 = v0 + bd[0];
            float l1 = v1 + bd[1];
            out[b * C_ + 0] = 1.f / (1.f + __expf(-l0));
            out[b * C_ + 1] = 1.f / (1.f + __expf(-l1));
        }
    }
}

// ---------------------------------------------------------------------------
extern "C" void kernel_launch(void* const* d_in, const int* in_sizes, int n_in,
                              void* d_out, int out_size, void* d_ws, size_t ws_size,
                              hipStream_t stream) {
    const int*   tokens = (const int*)  d_in[0];  // [B,T] int32
    const float* E      = (const float*)d_in[1];  // [V,D]
    const float* W      = (const float*)d_in[2];  // [D,H]
    const float* U      = (const float*)d_in[3];  // [H,H]
    const float* bias   = (const float*)d_in[4];  // [H]
    const float* Wd     = (const float*)d_in[5];  // [H,C]
    const float* bd     = (const float*)d_in[6];  // [C]
    float* out = (float*)d_out;                   // [B,C]
    float* EW  = (float*)d_ws;                    // [V,H] scratch: 1.28 MB

    ew_kernel<<<(V_ * H_ + 255) / 256, 256, 0, stream>>>(E, W, bias, EW);
    rnn_kernel<<<B_, 256, 0, stream>>>(tokens, EW, U, Wd, bd, out);
}

// Round 7
// 364.006 us; speedup vs baseline: 1.0025x; 1.0025x over previous
//
#include <hip/hip_runtime.h>

#define B_ 256
#define T_ 1024
#define V_ 5000
#define D_ 100
#define H_ 64
#define C_ 2

// ---------------------------------------------------------------------------
// Kernel 1: EW[v][h] = sum_d E[v][d] * W[d][h] + b[h]
// ---------------------------------------------------------------------------
__global__ __launch_bounds__(256) void ew_kernel(const float* __restrict__ E,
                                                 const float* __restrict__ W,
                                                 const float* __restrict__ bias,
                                                 float* __restrict__ EW) {
    int idx = blockIdx.x * 256 + threadIdx.x;   // 0 .. V_*H_
    if (idx >= V_ * H_) return;
    int h = idx & (H_ - 1);
    int v = idx >> 6;
    float acc = bias[h];
    const float* Erow = E + v * D_;
    #pragma unroll 4
    for (int d = 0; d < D_; ++d) {
        acc = fmaf(Erow[d], W[d * H_ + h], acc);
    }
    EW[idx] = acc;
}

// ---------------------------------------------------------------------------
// Kernel 2: per-batch RNN. One wave per batch element (R6's 4-wave split-K
// regressed: per-step barrier + LDS round-trip > saved VALU).
//
// R4/R5 accounting: marginal inst cost ~0.8 cyc; the step is dominated by a
// ~450-cyc serial-LATENCY floor (LDS b128 pacing into the fma chains + chain
// depth). This round removes memory from the dot entirely:
//  - amdgpu_waves_per_eu(1,1): pins the RA's occupancy target to 1 wave/SIMD
//    (full ~512 VGPR budget). This was the missing knob in R1-R3 -- with
//    only launch_bounds the RA spilled/rematted a 64-element U column.
//  - U column in 64 VGPRs: global loads + volatile-asm launder (cannot be
//    rematerialized; with the budget pinned there is no reason to spill).
//    Kills 16 ds_read_b128/step (~200 cyc of LDS pacing on the chain).
//  - 8 accumulators x 8-deep fma chains (dep depth 64 -> 32 cyc).
// Success indicator: VGPR_Count >= ~150. Failure: WRITE_SIZE jump = spill.
// ---------------------------------------------------------------------------
__device__ __forceinline__ float readlane_f(float v, int lane) {
    return __uint_as_float(__builtin_amdgcn_readlane(__float_as_uint(v), lane));
}

__global__ __launch_bounds__(64)
__attribute__((amdgpu_waves_per_eu(1, 1)))
void rnn_kernel(const int* __restrict__ tokens,
                const float* __restrict__ EW,
                const float* __restrict__ U,
                const float* __restrict__ Wd,
                const float* __restrict__ bd,
                float* __restrict__ out) {
    const int b = blockIdx.x;     // batch element
    const int j = threadIdx.x;    // 0..63 : hidden unit

    __shared__ int sh_tok[T_ + 2];   // 4 KB + pad

    const int* tok = tokens + b * T_;
    #pragma unroll
    for (int k = 0; k < T_ / H_; ++k) {
        sh_tok[k * H_ + j] = tok[k * H_ + j];    // coalesced
    }
    if (j < 2) sh_tok[T_ + j] = 0;               // pad: kills tail guard
    __syncthreads();

    // ---- U column j -> 64 VGPRs (one-time, coalesced, L2-broadcast) ----
    float u[H_];
    #pragma unroll
    for (int i = 0; i < H_; ++i) {
        float v = U[i * H_ + j];
        asm volatile("" : "+v"(v));   // opaque def: no remat of the load
        u[i] = v;
    }

    float h = 0.f;
    float pooled = 0.f;

    // 2-step-deep xw prefetch pipeline
    int2 tkA = *(const int2*)&sh_tok[0];
    float xw0 = EW[tkA.x * H_ + j];
    float xw1 = EW[tkA.y * H_ + j];

    // one recurrence step: register-only dot + clampless tanh + mask + pool
    #define RNN_STEP(tokv, xwv)                                          \
    {                                                                    \
        float a0 = 0.f, a1 = 0.f, a2 = 0.f, a3 = 0.f;                    \
        float a4 = 0.f, a5 = 0.f, a6 = 0.f, a7 = 0.f;                    \
        _Pragma("unroll")                                                \
        for (int m = 0; m < 8; ++m) {                                    \
            a0 = fmaf(readlane_f(h, 8 * m + 0), u[8 * m + 0], a0);       \
            a1 = fmaf(readlane_f(h, 8 * m + 1), u[8 * m + 1], a1);       \
            a2 = fmaf(readlane_f(h, 8 * m + 2), u[8 * m + 2], a2);       \
            a3 = fmaf(readlane_f(h, 8 * m + 3), u[8 * m + 3], a3);       \
            a4 = fmaf(readlane_f(h, 8 * m + 4), u[8 * m + 4], a4);       \
            a5 = fmaf(readlane_f(h, 8 * m + 5), u[8 * m + 5], a5);       \
            a6 = fmaf(readlane_f(h, 8 * m + 6), u[8 * m + 6], a6);       \
            a7 = fmaf(readlane_f(h, 8 * m + 7), u[8 * m + 7], a7);       \
        }                                                                \
        float x = (((a0 + a1) + (a2 + a3)) + ((a4 + a5) + (a6 + a7)))    \
                  + (xwv);                                               \
        float e = __expf(2.f * x);                                       \
        float r = __builtin_amdgcn_rcpf(e + 1.f);                        \
        float hn = fmaf(-2.f, r, 1.f);                                   \
        h = ((tokv) != 0) ? hn : h;                                      \
        pooled += h;                                                     \
    }

    for (int t = 0; t < T_; t += 2) {
        // prefetch steps t+2, t+3 (pad makes tail reads safe: EW[0])
        int2 tkB = *(const int2*)&sh_tok[t + 2];
        float xw2 = EW[tkB.x * H_ + j];
        float xw3 = EW[tkB.y * H_ + j];

        RNN_STEP(tkA.x, xw0);
        RNN_STEP(tkA.y, xw1);

        tkA = tkB;
        xw0 = xw2;
        xw1 = xw3;
    }
    #undef RNN_STEP

    // ---- epilogue: pooled mean -> dense(2) -> sigmoid ----
    float p = pooled * (1.0f / (float)T_);
    float v0 = p * Wd[j * C_ + 0];
    float v1 = p * Wd[j * C_ + 1];
    #pragma unroll
    for (int off = 32; off >= 1; off >>= 1) {
        v0 += __shfl_down(v0, off, 64);
        v1 += __shfl_down(v1, off, 64);
    }
    if (j == 0) {
        float l0 = v0 + bd[0];
        float l1 = v1 + bd[1];
        out[b * C_ + 0] = 1.f / (1.f + __expf(-l0));
        out[b * C_ + 1] = 1.f / (1.f + __expf(-l1));
    }
}

// ---------------------------------------------------------------------------
extern "C" void kernel_launch(void* const* d_in, const int* in_sizes, int n_in,
                              void* d_out, int out_size, void* d_ws, size_t ws_size,
                              hipStream_t stream) {
    const int*   tokens = (const int*)  d_in[0];  // [B,T] int32
    const float* E      = (const float*)d_in[1];  // [V,D]
    const float* W      = (const float*)d_in[2];  // [D,H]
    const float* U      = (const float*)d_in[3];  // [H,H]
    const float* bias   = (const float*)d_in[4];  // [H]
    const float* Wd     = (const float*)d_in[5];  // [H,C]
    const float* bd     = (const float*)d_in[6];  // [C]
    float* out = (float*)d_out;                   // [B,C]
    float* EW  = (float*)d_ws;                    // [V,H] scratch: 1.28 MB

    ew_kernel<<<(V_ * H_ + 255) / 256, 256, 0, stream>>>(E, W, bias, EW);
    rnn_kernel<<<B_, H_, 0, stream>>>(tokens, EW, U, Wd, bd, out);
}

// Round 8
// 340.470 us; speedup vs baseline: 1.0718x; 1.0691x over previous
//
#include <hip/hip_runtime.h>

#define B_ 256
#define T_ 1024
#define V_ 5000
#define D_ 100
#define H_ 64
#define C_ 2

// ---------------------------------------------------------------------------
// Kernel 1: EW[v][h] = sum_d E[v][d] * W[d][h] + b[h]
// ---------------------------------------------------------------------------
__global__ __launch_bounds__(256) void ew_kernel(const float* __restrict__ E,
                                                 const float* __restrict__ W,
                                                 const float* __restrict__ bias,
                                                 float* __restrict__ EW) {
    int idx = blockIdx.x * 256 + threadIdx.x;   // 0 .. V_*H_
    if (idx >= V_ * H_) return;
    int h = idx & (H_ - 1);
    int v = idx >> 6;
    float acc = bias[h];
    const float* Erow = E + v * D_;
    #pragma unroll 4
    for (int d = 0; d < D_; ++d) {
        acc = fmaf(Erow[d], W[d * H_ + h], acc);
    }
    EW[idx] = acc;
}

// ---------------------------------------------------------------------------
// Kernel 2: per-batch RNN. One wave per batch element.
//
// R7 post-mortem: with U fully register-resident (VGPR=132) the step STILL
// costs 689 cyc (~6.4 cyc per readlane->fma pair). Diagnosis: the
// "VALU writes SGPR (v_readlane) -> VALU reads that SGPR (v_fma)" hazard,
// paid 64x/step because the scheduler pairs each fma with its readlane.
// Fix this round: batch 32 readlanes into 32 SGPRs, sched_barrier, then
// 32 fmas (operand written >=64 cyc earlier -> hazard amortized), repeat.
// Same inst count, no per-pair stalls.
// Failure signature: dur unchanged => floor is readlane latency, not the
// hazard -> switch broadcast to the DS pipe next.
// ---------------------------------------------------------------------------
__device__ __forceinline__ float readlane_f(float v, int lane) {
    return __uint_as_float(__builtin_amdgcn_readlane(__float_as_uint(v), lane));
}

__global__ __launch_bounds__(64)
__attribute__((amdgpu_waves_per_eu(1, 1)))
void rnn_kernel(const int* __restrict__ tokens,
                const float* __restrict__ EW,
                const float* __restrict__ U,
                const float* __restrict__ Wd,
                const float* __restrict__ bd,
                float* __restrict__ out) {
    const int b = blockIdx.x;     // batch element
    const int j = threadIdx.x;    // 0..63 : hidden unit

    __shared__ int sh_tok[T_ + 2];   // 4 KB + pad

    const int* tok = tokens + b * T_;
    #pragma unroll
    for (int k = 0; k < T_ / H_; ++k) {
        sh_tok[k * H_ + j] = tok[k * H_ + j];    // coalesced
    }
    if (j < 2) sh_tok[T_ + j] = 0;               // pad: kills tail guard
    __syncthreads();

    // ---- U column j -> 64 VGPRs (validated in R7: VGPR_Count=132) ----
    float u[H_];
    #pragma unroll
    for (int i = 0; i < H_; ++i) {
        float v = U[i * H_ + j];
        asm volatile("" : "+v"(v));   // opaque def: no remat of the load
        u[i] = v;
    }

    float h = 0.f;
    float pooled = 0.f;

    // 2-step-deep xw prefetch pipeline
    int2 tkA = *(const int2*)&sh_tok[0];
    float xw0 = EW[tkA.x * H_ + j];
    float xw1 = EW[tkA.y * H_ + j];

    // one recurrence step. hs[] values are wave-uniform (readlane results)
    // -> live in SGPRs; the fma blocks read them as SGPR constants long
    // after the write, so the SGPR-read-after-VALU-write hazard is gone.
    #define RNN_STEP(tokv, xwv)                                          \
    {                                                                    \
        float a0 = 0.f, a1 = 0.f, a2 = 0.f, a3 = 0.f;                    \
        float a4 = 0.f, a5 = 0.f, a6 = 0.f, a7 = 0.f;                    \
        float hs[H_];                                                    \
        _Pragma("unroll")                                                \
        for (int i = 0; i < 32; ++i) hs[i] = readlane_f(h, i);           \
        __builtin_amdgcn_sched_barrier(0);                               \
        _Pragma("unroll")                                                \
        for (int m = 0; m < 4; ++m) {                                    \
            a0 = fmaf(hs[8 * m + 0], u[8 * m + 0], a0);                  \
            a1 = fmaf(hs[8 * m + 1], u[8 * m + 1], a1);                  \
            a2 = fmaf(hs[8 * m + 2], u[8 * m + 2], a2);                  \
            a3 = fmaf(hs[8 * m + 3], u[8 * m + 3], a3);                  \
            a4 = fmaf(hs[8 * m + 4], u[8 * m + 4], a4);                  \
            a5 = fmaf(hs[8 * m + 5], u[8 * m + 5], a5);                  \
            a6 = fmaf(hs[8 * m + 6], u[8 * m + 6], a6);                  \
            a7 = fmaf(hs[8 * m + 7], u[8 * m + 7], a7);                  \
        }                                                                \
        __builtin_amdgcn_sched_barrier(0);                               \
        _Pragma("unroll")                                                \
        for (int i = 32; i < 64; ++i) hs[i] = readlane_f(h, i);          \
        __builtin_amdgcn_sched_barrier(0);                               \
        _Pragma("unroll")                                                \
        for (int m = 4; m < 8; ++m) {                                    \
            a0 = fmaf(hs[8 * m + 0], u[8 * m + 0], a0);                  \
            a1 = fmaf(hs[8 * m + 1], u[8 * m + 1], a1);                  \
            a2 = fmaf(hs[8 * m + 2], u[8 * m + 2], a2);                  \
            a3 = fmaf(hs[8 * m + 3], u[8 * m + 3], a3);                  \
            a4 = fmaf(hs[8 * m + 4], u[8 * m + 4], a4);                  \
            a5 = fmaf(hs[8 * m + 5], u[8 * m + 5], a5);                  \
            a6 = fmaf(hs[8 * m + 6], u[8 * m + 6], a6);                  \
            a7 = fmaf(hs[8 * m + 7], u[8 * m + 7], a7);                  \
        }                                                                \
        float x = (((a0 + a1) + (a2 + a3)) + ((a4 + a5) + (a6 + a7)))    \
                  + (xwv);                                               \
        float e = __expf(2.f * x);                                       \
        float r = __builtin_amdgcn_rcpf(e + 1.f);                        \
        float hn = fmaf(-2.f, r, 1.f);                                   \
        h = ((tokv) != 0) ? hn : h;                                      \
        pooled += h;                                                     \
    }

    for (int t = 0; t < T_; t += 2) {
        // prefetch steps t+2, t+3 (pad makes tail reads safe: EW[0])
        int2 tkB = *(const int2*)&sh_tok[t + 2];
        float xw2 = EW[tkB.x * H_ + j];
        float xw3 = EW[tkB.y * H_ + j];

        RNN_STEP(tkA.x, xw0);
        RNN_STEP(tkA.y, xw1);

        tkA = tkB;
        xw0 = xw2;
        xw1 = xw3;
    }
    #undef RNN_STEP

    // ---- epilogue: pooled mean -> dense(2) -> sigmoid ----
    float p = pooled * (1.0f / (float)T_);
    float v0 = p * Wd[j * C_ + 0];
    float v1 = p * Wd[j * C_ + 1];
    #pragma unroll
    for (int off = 32; off >= 1; off >>= 1) {
        v0 += __shfl_down(v0, off, 64);
        v1 += __shfl_down(v1, off, 64);
    }
    if (j == 0) {
        float l0 = v0 + bd[0];
        float l1 = v1 + bd[1];
        out[b * C_ + 0] = 1.f / (1.f + __expf(-l0));
        out[b * C_ + 1] = 1.f / (1.f + __expf(-l1));
    }
}

// ---------------------------------------------------------------------------
extern "C" void kernel_launch(void* const* d_in, const int* in_sizes, int n_in,
                              void* d_out, int out_size, void* d_ws, size_t ws_size,
                              hipStream_t stream) {
    const int*   tokens = (const int*)  d_in[0];  // [B,T] int32
    const float* E      = (const float*)d_in[1];  // [V,D]
    const float* W      = (const float*)d_in[2];  // [D,H]
    const float* U      = (const float*)d_in[3];  // [H,H]
    const float* bias   = (const float*)d_in[4];  // [H]
    const float* Wd     = (const float*)d_in[5];  // [H,C]
    const float* bd     = (const float*)d_in[6];  // [C]
    float* out = (float*)d_out;                   // [B,C]
    float* EW  = (float*)d_ws;                    // [V,H] scratch: 1.28 MB

    ew_kernel<<<(V_ * H_ + 255) / 256, 256, 0, stream>>>(E, W, bias, EW);
    rnn_kernel<<<B_, H_, 0, stream>>>(tokens, EW, U, Wd, bd, out);
}